// Round 11
// baseline (925.886 us; speedup 1.0000x reference)
//
#include <hip/hip_runtime.h>
#include <hip/hip_fp16.h>
#include <math.h>
#include <cstdint>
#include <cstddef>

#define NGRAPH 64
#define NN 200
#define ADJN 40000
#define DIN 4000
#define NNODE 12800

typedef float    f32x4 __attribute__((ext_vector_type(4)));
typedef _Float16 f16x8 __attribute__((ext_vector_type(8)));
typedef _Float16 f16x4 __attribute__((ext_vector_type(4)));
typedef _Float16 f16x2 __attribute__((ext_vector_type(2)));
typedef short    bf8v  __attribute__((ext_vector_type(8)));
typedef short    bf4v  __attribute__((ext_vector_type(4)));

union BF8U  { bf8v v; bf4v h[2]; };
union F16X8U{ f16x8 v; f16x4 h[2]; f16x2 p[4]; };
union U4F   { uint4 u; unsigned w[4]; };

__device__ __forceinline__ unsigned short f2bf(float f) {
  unsigned u = __float_as_uint(f);
  return (unsigned short)((u + 0x7fffu + ((u >> 16) & 1u)) >> 16);
}
__device__ __forceinline__ float bf2f(unsigned short s) {
  return __uint_as_float(((unsigned)s) << 16);
}
__device__ __forceinline__ float gelu_f(float x) {
  return x * 0.5f * (1.0f + erff(x * 0.70710678118654752f));
}

#if defined(__has_builtin)
#if __has_builtin(__builtin_amdgcn_fdot2)
#define FDOT2(a, b, c) __builtin_amdgcn_fdot2((a), (b), (c), false)
#endif
#endif
#ifndef FDOT2
#define FDOT2(a, b, c) ((c) + (float)(a)[0] * (float)(b)[0] + (float)(a)[1] * (float)(b)[1])
#endif

// async global->LDS, 16B per lane; lptr must be wave-uniform (HW adds lane*16)
__device__ __forceinline__ void glds16(const _Float16* g, _Float16* l) {
  __builtin_amdgcn_global_load_lds(
      (const __attribute__((address_space(1))) void*)g,
      (__attribute__((address_space(3))) void*)l, 16, 0, 0);
}

// ---------------------------------------------------------------------------
// K0: raw_fc -> hi/lo bf16 split
// ---------------------------------------------------------------------------
__global__ __launch_bounds__(256) void prep_A(const float* __restrict__ A,
                                              short* __restrict__ Ahi,
                                              short* __restrict__ Alo) {
  const int i = blockIdx.x * 256 + threadIdx.x;  // 256000 exact
  const float v = A[i];
  const unsigned short h = f2bf(v);
  Ahi[i] = (short)h;
  Alo[i] = (short)f2bf(v - bf2f(h));
}

// ---------------------------------------------------------------------------
// K0b: all 4 GEMM weights: W[k][n] f32 -> Wt[n][k] f16 (fused, blockIdx.z)
// ---------------------------------------------------------------------------
__global__ __launch_bounds__(256) void transp_all(
    const float* __restrict__ W2l, const float* __restrict__ W2r,
    const float* __restrict__ W3l, const float* __restrict__ W3r,
    _Float16* __restrict__ T2l, _Float16* __restrict__ T2r,
    _Float16* __restrict__ T3l, _Float16* __restrict__ T3r) {
  __shared__ float tile[32][33];
  const int z = blockIdx.z;
  if (z >= 2 && blockIdx.y >= 16) return;
  const float* src = (z == 0) ? W2l : (z == 1) ? W2r : (z == 2) ? W3l : W3r;
  _Float16* dst = (z == 0) ? T2l : (z == 1) ? T2r : (z == 2) ? T3l : T3r;
  const int N = (z < 2) ? 1024 : 512;
  const int K = 1024;
  const int bk = blockIdx.x * 32, bn = blockIdx.y * 32;
  const int tx = threadIdx.x & 31, ty = threadIdx.x >> 5;
#pragma unroll
  for (int r = 0; r < 32; r += 8) tile[ty + r][tx] = src[(size_t)(bk + ty + r) * N + bn + tx];
  __syncthreads();
#pragma unroll
  for (int r = 0; r < 32; r += 8)
    dst[(size_t)(bn + ty + r) * K + bk + tx] = (_Float16)tile[tx][ty + r];
}

// ---------------------------------------------------------------------------
// K1: adj = sigmoid(raw_fc @ gbW + gbb); split-bf16 MFMA.
// ---------------------------------------------------------------------------
#define BA_LOADW(WV, K0)                                                        \
  _Pragma("unroll") for (int q = 0; q < 8; ++q)                                 \
    WV[q] = W[(size_t)((K0) + kgrp * 8 + q) * ADJN + n0 + nn];

#define BA_CONV(PB, WV)                                                         \
  { bf4v h0, h1, l0, l1;                                                        \
    _Pragma("unroll") for (int i = 0; i < 4; ++i) {                             \
      unsigned short hh = (unsigned short)(__float_as_uint(WV[i]) >> 16);       \
      h0[i] = (short)hh;                                                        \
      l0[i] = (short)f2bf(WV[i] - bf2f(hh));                                    \
    }                                                                           \
    _Pragma("unroll") for (int i = 0; i < 4; ++i) {                             \
      unsigned short hh = (unsigned short)(__float_as_uint(WV[4 + i]) >> 16);   \
      h1[i] = (short)hh;                                                        \
      l1[i] = (short)f2bf(WV[4 + i] - bf2f(hh));                                \
    }                                                                           \
    *(bf4v*)(Wh[PB] + nn * 44 + kgrp * 8)     = h0;                             \
    *(bf4v*)(Wh[PB] + nn * 44 + kgrp * 8 + 4) = h1;                             \
    *(bf4v*)(Wl[PB] + nn * 44 + kgrp * 8)     = l0;                             \
    *(bf4v*)(Wl[PB] + nn * 44 + kgrp * 8 + 4) = l1;                             \
  }

#define BA_MFMA(PB, AHC, ALC)                                                   \
  _Pragma("unroll") for (int j = 0; j < 4; ++j) {                               \
    const int bc = (j * 16 + (lane & 15)) * 44 + kb;                            \
    BF8U bh, bl;                                                                \
    bh.h[0] = *(const bf4v*)(Wh[PB] + bc);                                      \
    bh.h[1] = *(const bf4v*)(Wh[PB] + bc + 4);                                  \
    bl.h[0] = *(const bf4v*)(Wl[PB] + bc);                                      \
    bl.h[1] = *(const bf4v*)(Wl[PB] + bc + 4);                                  \
    acc[j] = __builtin_amdgcn_mfma_f32_16x16x32_bf16(AHC, bh.v, acc[j], 0, 0, 0); \
    acc[j] = __builtin_amdgcn_mfma_f32_16x16x32_bf16(AHC, bl.v, acc[j], 0, 0, 0); \
    acc[j] = __builtin_amdgcn_mfma_f32_16x16x32_bf16(ALC, bh.v, acc[j], 0, 0, 0); \
  }

#define BA_LOADA(AH, AL, K0)                                                    \
  AH = *(const bf8v*)(Ahi + (size_t)arow * DIN + (K0) + kb);                    \
  AL = *(const bf8v*)(Alo + (size_t)arow * DIN + (K0) + kb);

__global__ __launch_bounds__(256) void build_adj(
    const short* __restrict__ Ahi, const short* __restrict__ Alo,
    const float* __restrict__ W, const float* __restrict__ bias,
    float* __restrict__ adj) {
  __shared__ short Wh[2][64 * 44], Wl[2][64 * 44];
  const int t = threadIdx.x, wave = t >> 6, lane = t & 63;
  const int n0 = blockIdx.x * 64;
  const int nn = t & 63, kgrp = t >> 6;   // staging coords: one n, 8 k
  const int kb = (lane >> 4) * 8;
  const int arow = wave * 16 + (lane & 15);
  f32x4 acc[4] = {};
  float wva[8], wvb[8];
  bf8v ahs0, als0, ahs1, als1;
  BA_LOADW(wva, 0)
  BA_LOADA(ahs0, als0, 0)
  BA_LOADW(wvb, 32)
  BA_LOADA(ahs1, als1, 32)
  BA_CONV(0, wva)
  for (int it = 0; it < 124; it += 2) {
    __syncthreads();
    {
      const bf8v ahc = ahs0, alc = als0;
      if (it + 2 < 125) {
        const int k2 = (it + 2) * 32;
        BA_LOADW(wva, k2)
        BA_LOADA(ahs0, als0, k2)
      }
      BA_MFMA(0, ahc, alc)
      BA_CONV(1, wvb)
    }
    __syncthreads();
    {
      const bf8v ahc = ahs1, alc = als1;
      if (it + 3 < 125) {
        const int k2 = (it + 3) * 32;
        BA_LOADW(wvb, k2)
        BA_LOADA(ahs1, als1, k2)
      }
      BA_MFMA(1, ahc, alc)
      if (it + 2 < 125) BA_CONV(0, wva)
    }
  }
  __syncthreads();
  BA_MFMA(0, ahs0, als0)
#pragma unroll
  for (int j = 0; j < 4; ++j) {
    const int col = n0 + j * 16 + (lane & 15);
    const float bb = bias[col];
#pragma unroll
    for (int vv = 0; vv < 4; ++vv) {
      const int row = wave * 16 + (lane >> 4) * 4 + vv;
      float x = acc[j][vv] + bb;
      adj[(size_t)row * ADJN + col] = 1.0f / (1.0f + __expf(-x));
    }
  }
}

// ---------------------------------------------------------------------------
// K2: adjS = 0.5*(adj + adj^T), LDS-tiled
// ---------------------------------------------------------------------------
__global__ __launch_bounds__(256) void symmetrize(const float* __restrict__ adj,
                                                  float* __restrict__ adjS) {
  __shared__ float tl[64][65];
  const int g = blockIdx.x;
  const int i0 = (blockIdx.y >> 2) * 64, j0 = (blockIdx.y & 3) * 64;
  const int tx = threadIdx.x & 63, ty = threadIdx.x >> 6;
  const float* ag = adj + (size_t)g * ADJN;
#pragma unroll
  for (int r = 0; r < 64; r += 4) {
    const int jr = j0 + ty + r;
    tl[ty + r][tx] = (jr < NN && i0 + tx < NN) ? ag[jr * NN + i0 + tx] : 0.f;
  }
  __syncthreads();
#pragma unroll
  for (int r = 0; r < 64; r += 4) {
    const int i = i0 + ty + r, j = j0 + tx;
    if (i < NN && j < NN)
      adjS[(size_t)g * ADJN + i * NN + j] = 0.5f * (ag[i * NN + j] + tl[tx][ty + r]);
  }
}

// ---------------------------------------------------------------------------
// K2b: per-row mean / std(ddof=1)
// ---------------------------------------------------------------------------
__global__ __launch_bounds__(256) void rowstats(const float* __restrict__ adjS,
                                                float* __restrict__ meanv,
                                                float* __restrict__ stdv) {
  const int row = blockIdx.x * 4 + (threadIdx.x >> 6);
  const int lane = threadIdx.x & 63;
  const float* r = adjS + (size_t)row * NN;
  float s = 0.f, q = 0.f;
#pragma unroll
  for (int k = 0; k < 4; ++k) {
    int i = k * 64 + lane;
    if (i < NN) { float v = r[i]; s += v; q += v * v; }
  }
#pragma unroll
  for (int off = 32; off > 0; off >>= 1) { s += __shfl_xor(s, off); q += __shfl_xor(q, off); }
  if (lane == 0) {
    float m = s * (1.0f / 200.0f);
    float var = (q - 200.0f * m * m) * (1.0f / 199.0f);
    var = fmaxf(var, 0.f);
    meanv[row] = m;
    stdv[row] = sqrtf(var) + 1e-6f;
  }
}

// ---------------------------------------------------------------------------
// K3: fused radix-select (4-copy hist) + per-dst neighbor lists. 64 blocks.
// ---------------------------------------------------------------------------
__global__ __launch_bounds__(1024) void radix_lists(
    const float* __restrict__ adjS,
    int* __restrict__ cnt1, int* __restrict__ cnt2,
    unsigned char* __restrict__ list1, unsigned char* __restrict__ list2) {
  __shared__ unsigned hist[4 * 2048];
  __shared__ unsigned s_pref, s_cA;
  const int g = blockIdx.x, t = threadIdx.x, lane = t & 63, wave = t >> 6;
  const float* v = adjS + (size_t)g * ADJN;
  unsigned prefix = 0, pmask = 0, cA = 0;
  const int shifts[3] = {20, 9, 0};
  const int widths[3] = {2048, 2048, 512};
  for (int pass = 0; pass < 3; ++pass) {
    const int nb = widths[pass], sh = shifts[pass];
    for (int i = t; i < 8192; i += 1024) hist[i] = 0u;
    __syncthreads();
    const int cpy = (lane & 3) * 2048;
    for (int e = t; e < ADJN; e += 1024) {
      unsigned u = __float_as_uint(v[e]);
      if ((u & pmask) == prefix) atomicAdd(&hist[cpy + ((u >> sh) & (nb - 1))], 1u);
    }
    __syncthreads();
    if (t < 64) {
      const int CH = nb >> 6;
      unsigned lsum = 0;
      for (int i = 0; i < CH; ++i) {
        const int b = t * CH + i;
        lsum += hist[b] + hist[2048 + b] + hist[4096 + b] + hist[6144 + b];
      }
      unsigned s = lsum;
#pragma unroll
      for (int off = 1; off < 64; off <<= 1) {
        unsigned o = __shfl_down(s, off);
        if (lane + off < 64) s += o;
      }
      const unsigned need = 10000u - cA;
      unsigned sn = __shfl_down(s, 1);
      const unsigned snext = (lane == 63) ? 0u : sn;
      if (s >= need && snext < need) {
        unsigned cum = snext;
        int bsel = t * CH;
        for (int i = CH - 1; i >= 0; --i) {
          const int b = t * CH + i;
          unsigned hb = hist[b] + hist[2048 + b] + hist[4096 + b] + hist[6144 + b];
          if (cum + hb >= need) { bsel = b; break; }
          cum += hb;
        }
        s_pref = prefix | ((unsigned)bsel << sh);
        s_cA = cA + cum;
      }
    }
    __syncthreads();
    prefix = s_pref; cA = s_cA;
    pmask |= (unsigned)(widths[pass] - 1) << sh;
    __syncthreads();
  }
  const float tv = __uint_as_float(prefix);
  for (int j = wave; j < NN; j += 16) {
    const float* row = adjS + (size_t)g * ADJN + (size_t)j * NN;
    unsigned char* l1 = list1 + ((size_t)g * NN + j) * NN;
    unsigned char* l2 = list2 + ((size_t)g * NN + j) * NN;
    int c1 = 0, c2 = 0;
#pragma unroll
    for (int r = 0; r < 4; ++r) {
      int i = r * 64 + lane;
      bool p1 = false, p2 = false;
      if (i < NN) { float vv = row[i]; p1 = (vv >= tv); p2 = p1 && (i != j); }
      unsigned long long b1 = __ballot(p1);
      unsigned long long b2 = __ballot(p2);
      unsigned long long below = (lane == 0) ? 0ull : ((~0ull) >> (64 - lane));
      if (p1) l1[c1 + __popcll(b1 & below)] = (unsigned char)i;
      if (p2) l2[c2 + __popcll(b2 & below)] = (unsigned char)i;
      c1 += (int)__popcll(b1); c2 += (int)__popcll(b2);
    }
    if (lane == 0) {
      l2[c2] = (unsigned char)j;
      cnt1[g * NN + j] = c1;
      cnt2[g * NN + j] = c2 + 1;
    }
  }
}

// ---------------------------------------------------------------------------
// K6: fused node-MLP(2->8 gelu ->16)+LN(16) -> xl1/xr1 via MFMA (K=16 padded)
// ---------------------------------------------------------------------------
__global__ __launch_bounds__(256) void lin16_fused(
    const float* __restrict__ meanv, const float* __restrict__ stdv,
    const float* __restrict__ feW1, const float* __restrict__ feb1,
    const float* __restrict__ feW2, const float* __restrict__ feb2,
    const float* __restrict__ ln_g, const float* __restrict__ ln_b,
    const float* __restrict__ Wl, const float* __restrict__ bl,
    const float* __restrict__ Wr, const float* __restrict__ br,
    _Float16* __restrict__ outl, _Float16* __restrict__ outr) {
  __shared__ _Float16 Wt[1024 * 20];
  __shared__ float x0s[16][17];
  const int t = threadIdx.x, wave = t >> 6, lane = t & 63;
  const int mbase = blockIdx.x * 16;
  {
    const int n = t >> 4, o = t & 15;
    const float mu = meanv[mbase + n], sd = stdv[mbase + n];
    float h1[8];
#pragma unroll
    for (int k = 0; k < 8; ++k) h1[k] = gelu_f(mu * feW1[k] + sd * feW1[8 + k] + feb1[k]);
    float h2 = feb2[o];
#pragma unroll
    for (int k = 0; k < 8; ++k) h2 += h1[k] * feW2[k * 16 + o];
    float s = h2;
#pragma unroll
    for (int off = 1; off < 16; off <<= 1) s += __shfl_xor(s, off);
    s *= (1.0f / 16.0f);
    const float d = h2 - s;
    float vv = d * d;
#pragma unroll
    for (int off = 1; off < 16; off <<= 1) vv += __shfl_xor(vv, off);
    vv *= (1.0f / 16.0f);
    x0s[n][o] = d * (1.0f / sqrtf(vv + 1e-5f)) * ln_g[o] + ln_b[o];
  }
  __syncthreads();
  const int mrow = lane & 15, kg = lane >> 4;
  F16X8U af;
#pragma unroll
  for (int q = 0; q < 8; ++q) af.v[q] = (_Float16)0.f;
  if (kg < 2) {
#pragma unroll
    for (int q = 0; q < 8; ++q) af.v[q] = (_Float16)x0s[mrow][kg * 8 + q];
  }
#pragma unroll
  for (int mat = 0; mat < 2; ++mat) {
    if (mat) __syncthreads();
    const float* Wsrc = mat ? Wr : Wl;
    for (int i = t; i < 4096; i += 256) {
      const int k = i >> 8, n4 = (i & 255) * 4;
      float4 wv = *(const float4*)(Wsrc + (size_t)k * 1024 + n4);
      Wt[(n4 + 0) * 20 + k] = (_Float16)wv.x;
      Wt[(n4 + 1) * 20 + k] = (_Float16)wv.y;
      Wt[(n4 + 2) * 20 + k] = (_Float16)wv.z;
      Wt[(n4 + 3) * 20 + k] = (_Float16)wv.w;
    }
    __syncthreads();
    const float* bias = mat ? br : bl;
    _Float16* out = mat ? outr : outl;
#pragma unroll
    for (int nt = 0; nt < 16; ++nt) {
      const int n0 = wave * 256 + nt * 16;
      F16X8U bfv;
#pragma unroll
      for (int q = 0; q < 8; ++q) bfv.v[q] = (_Float16)0.f;
      if (kg < 2) bfv.v = *(const f16x8*)(Wt + (n0 + mrow) * 20 + kg * 8);
      f32x4 acc = {};
      acc = __builtin_amdgcn_mfma_f32_16x16x32_f16(af.v, bfv.v, acc, 0, 0, 0);
      const int col = n0 + mrow;
      const float bb = bias[col];
#pragma unroll
      for (int j = 0; j < 4; ++j)
        out[(size_t)(mbase + kg * 4 + j) * 1024 + col] = (_Float16)(acc[j] + bb);
    }
  }
}

// ---------------------------------------------------------------------------
// K9: NT-GEMM 128x128 tile, BK=64, dbuf LDS via global_load_lds (16B)
// ---------------------------------------------------------------------------
__global__ __launch_bounds__(256, 2) void gemm_nt(
    const _Float16* __restrict__ A,
    const _Float16* __restrict__ Bt0, const _Float16* __restrict__ Bt1,
    const float* __restrict__ b0, const float* __restrict__ b1,
    _Float16* __restrict__ out0, _Float16* __restrict__ out1,
    int Nhalf, int tilesPerHalf) {
  __shared__ _Float16 As[2][128 * 64];
  __shared__ _Float16 Bs[2][128 * 64];
  const int mbase = blockIdx.y * 128;
  const int hsel = blockIdx.x / tilesPerHalf;
  const int ncol0 = (blockIdx.x % tilesPerHalf) * 128;
  const _Float16* Bt = hsel ? Bt1 : Bt0;
  const float* bias = hsel ? b1 : b0;
  _Float16* out = hsel ? out1 : out0;
  const int t = threadIdx.x, wave = t >> 6, lane = t & 63;
  const int wm = wave >> 1, wn = wave & 1;
  f32x4 acc[4][4] = {};
  const int srow = lane >> 3;
  const int sg = (lane & 7) ^ srow;
#pragma unroll
  for (int c = 0; c < 4; ++c) {
    const int rbase = wave * 32 + c * 8;
    glds16(A + (size_t)(mbase + rbase + srow) * 1024 + sg * 8, As[0] + rbase * 64);
    glds16(Bt + (size_t)(ncol0 + rbase + srow) * 1024 + sg * 8, Bs[0] + rbase * 64);
  }
  __syncthreads();
  for (int kt = 0; kt < 16; ++kt) {
    const int p = kt & 1;
    if (kt < 15) {
      const int k0 = (kt + 1) * 64;
#pragma unroll
      for (int c = 0; c < 4; ++c) {
        const int rbase = wave * 32 + c * 8;
        glds16(A + (size_t)(mbase + rbase + srow) * 1024 + k0 + sg * 8, As[p ^ 1] + rbase * 64);
        glds16(Bt + (size_t)(ncol0 + rbase + srow) * 1024 + k0 + sg * 8, Bs[p ^ 1] + rbase * 64);
      }
    }
#pragma unroll
    for (int ks = 0; ks < 2; ++ks) {
      F16X8U af[4], bfv[4];
#pragma unroll
      for (int m = 0; m < 4; ++m) {
        const int row = wm * 64 + m * 16 + (lane & 15);
        const int kk = ks * 32 + (lane >> 4) * 8;
        af[m].v = *(const f16x8*)(As[p] + row * 64 + (kk ^ ((row & 7) << 3)));
      }
#pragma unroll
      for (int j = 0; j < 4; ++j) {
        const int row = wn * 64 + j * 16 + (lane & 15);
        const int kk = ks * 32 + (lane >> 4) * 8;
        bfv[j].v = *(const f16x8*)(Bs[p] + row * 64 + (kk ^ ((row & 7) << 3)));
      }
#pragma unroll
      for (int j = 0; j < 4; ++j)
#pragma unroll
        for (int m = 0; m < 4; ++m)
          acc[m][j] = __builtin_amdgcn_mfma_f32_16x16x32_f16(af[m].v, bfv[j].v, acc[m][j], 0, 0, 0);
    }
    __syncthreads();
  }
#pragma unroll
  for (int j = 0; j < 4; ++j) {
    const int col = ncol0 + wn * 64 + j * 16 + (lane & 15);
    const float bb = bias[col];
#pragma unroll
    for (int m = 0; m < 4; ++m) {
#pragma unroll
      for (int vv = 0; vv < 4; ++vv) {
        const int row = mbase + wm * 64 + m * 16 + (lane >> 4) * 4 + vv;
        out[(size_t)row * Nhalf + col] = (_Float16)(acc[m][j][vv] + bb);
      }
    }
  }
}

// ---------------------------------------------------------------------------
// K7: GATv2 layer v4: store-side XOR swizzle (slot = g ^ (s&(NGR-1))) so
// logit-phase xr/att reads are wave-uniform broadcasts; xa gathers spread
// by neighbor id. Packed (alpha|s) agg.
// ---------------------------------------------------------------------------
template <int C, int HC>
__global__ __launch_bounds__(1024, 4) void gat_layer(
    const _Float16* __restrict__ xlb, const _Float16* __restrict__ xrb,
    const float* __restrict__ attw, const float* __restrict__ biasw,
    const int* __restrict__ cnts, const unsigned char* __restrict__ lists,
    _Float16* __restrict__ outb) {
  extern __shared__ char smem[];
  constexpr int XLB = 200 * C * 2;
  constexpr int XRW = 16 * C * 2;
  _Float16* xr_s = (_Float16*)(smem + XLB);
  unsigned* awp = (unsigned*)(smem + XLB + XRW);              // 16*200*4
  unsigned* att_s = (unsigned*)(smem + XLB + XRW + 12800);
  const int g = blockIdx.x;
  const int hd = blockIdx.y;
  const int t = threadIdx.x, wave = t >> 6, lane = t & 63;
  constexpr int NGR = C / 8;          // 16B granules per row
  constexpr int GRP = (C == 128) ? 16 : 32;
  constexpr int NG = 64 / GRP;
  const int grp = lane / GRP, li = lane % GRP;

  for (int ch = t; ch < 200 * NGR; ch += 1024) {
    const int node = ch / NGR, gr = ch % NGR;
    *(f16x8*)((_Float16*)smem + node * C + (gr ^ (node & (NGR - 1))) * 8) =
        *(const f16x8*)(xlb + (size_t)(g * 200 + node) * HC + hd * C + gr * 8);
  }
  for (int i = t; i < C / 2; i += 1024) {
    f16x2 a;
    a[0] = (_Float16)attw[hd * C + 2 * i];
    a[1] = (_Float16)attw[hd * C + 2 * i + 1];
    att_s[i] = __builtin_bit_cast(unsigned, a);
  }
  __syncthreads();

  _Float16* xr_w = xr_s + wave * C;
  const uint4* att4 = (const uint4*)att_s;
  f16x8 xrreg;
  if (lane < NGR)
    xrreg = *(const f16x8*)(xrb + (size_t)(g * 200 + wave) * HC + hd * C + lane * 8);

  for (int jj = wave; jj < 200; jj += 16) {
    const int gn = g * 200 + jj;
    const int cnt = cnts[gn];
    const unsigned char* lst = lists + (size_t)gn * NN;
    if (lane < NGR) {
      *(f16x8*)(xr_w + lane * 8) = xrreg;
      if (jj + 16 < 200)
        xrreg = *(const f16x8*)(xrb + (size_t)(gn + 16) * HC + hd * C + lane * 8);
    }
    float lg[4] = {-INFINITY, -INFINITY, -INFINITY, -INFINITY};
    int sreg[4];
#pragma unroll
    for (int r = 0; r < 4; ++r) {
      const int e = (r << 6) + lane;
      if (e < cnt) {
        const int s = lst[e];
        sreg[r] = s;
        const int sw = s & (NGR - 1);
        const _Float16* xrow = (const _Float16*)(smem) + s * C;
        float accv[4] = {0.f, 0.f, 0.f, 0.f};
#pragma unroll 4
        for (int gi0 = 0; gi0 < NGR; ++gi0) {
          F16X8U xa, raa;
          xa.v = *(const f16x8*)(xrow + (gi0 ^ sw) * 8);
          raa.v = *(const f16x8*)(xr_w + gi0 * 8);
          U4F av; av.u = att4[gi0];
#pragma unroll
          for (int pq = 0; pq < 4; ++pq) {
            f16x2 z = xa.p[pq] + raa.p[pq];
            f16x2 zs = z * (_Float16)0.2f;
            f16x2 m = __builtin_elementwise_max(z, zs);
            accv[pq] = FDOT2(__builtin_bit_cast(f16x2, av.w[pq]), m, accv[pq]);
          }
        }
        lg[r] = (accv[0] + accv[1]) + (accv[2] + accv[3]);
      }
    }
    float mloc = fmaxf(fmaxf(lg[0], lg[1]), fmaxf(lg[2], lg[3]));
#pragma unroll
    for (int off = 32; off > 0; off >>= 1) mloc = fmaxf(mloc, __shfl_xor(mloc, off));
    float ex[4]; float ps = 0.f;
#pragma unroll
    for (int r = 0; r < 4; ++r) { ex[r] = __expf(lg[r] - mloc); ps += ex[r]; }
#pragma unroll
    for (int off = 32; off > 0; off >>= 1) ps += __shfl_xor(ps, off);
    const float denom = ps + 1e-16f;
#pragma unroll
    for (int r = 0; r < 4; ++r) {
      const int e = (r << 6) + lane;
      if (e < cnt) {
        const unsigned short ab =
            __builtin_bit_cast(unsigned short, (_Float16)(ex[r] / denom));
        awp[wave * 200 + e] = ((unsigned)ab << 16) | (unsigned)sreg[r];
      }
    }
    float o[8] = {};
#pragma unroll 4
    for (int e0 = 0; e0 < cnt; e0 += NG) {
      const int e = e0 + grp;
      if (e < cnt) {
        const unsigned v = awp[wave * 200 + e];
        const int s = v & 0xFF;
        const float a =
            (float)__builtin_bit_cast(_Float16, (unsigned short)(v >> 16));
        f16x8 xv = *(const f16x8*)((const _Float16*)smem + s * C +
                                   (li ^ (s & (NGR - 1))) * 8);
#pragma unroll
        for (int q = 0; q < 8; ++q) o[q] += a * (float)xv[q];
      }
    }
#pragma unroll
    for (int q = 0; q < 8; ++q) {
      if constexpr (GRP == 16) o[q] += __shfl_xor(o[q], 16);
      o[q] += __shfl_xor(o[q], 32);
    }
    if (grp == 0) {
      const int colb = hd * C + li * 8;
      f16x8 ov;
#pragma unroll
      for (int q = 0; q < 8; ++q) ov[q] = (_Float16)gelu_f(o[q] + biasw[colb + q]);
      *(f16x8*)(outb + (size_t)gn * HC + colb) = ov;
    }
  }
}

// ---------------------------------------------------------------------------
// K7-L3: GATv2 (H=1,C=512) chunked v4: store-side XOR swizzle + broadcasts
// ---------------------------------------------------------------------------
__global__ __launch_bounds__(1024, 4) void gat_l3(
    const _Float16* __restrict__ xlb, const _Float16* __restrict__ xrb,
    const float* __restrict__ attw, const float* __restrict__ biasw,
    const int* __restrict__ cnts, const unsigned char* __restrict__ lists,
    float* __restrict__ psum) {
  extern __shared__ char smem[];
  _Float16* xr_s = (_Float16*)(smem + 51200);
  float* plog = (float*)(smem + 64000);
  unsigned* plogp = (unsigned*)(smem + 64000);
  unsigned* att_s = (unsigned*)(smem + 104000);
  const int g = blockIdx.x, range = blockIdx.y, r0 = range * 50;
  const int t = threadIdx.x, wave = t >> 6, lane = t & 63;
  const int grp = lane >> 4, li = lane & 15;
  const uint4* att4 = (const uint4*)att_s;

  for (int chunk = 0; chunk < 4; ++chunk) {
    if (chunk) __syncthreads();
    for (int ch = t; ch < 200 * 16; ch += 1024) {
      const int node = ch >> 4, gr = ch & 15;
      *(f16x8*)((_Float16*)smem + node * 128 + (gr ^ (node & 15)) * 8) =
          *(const f16x8*)(xlb + (size_t)(g * 200 + node) * 512 + chunk * 128 + gr * 8);
    }
    for (int ch = t; ch < 50 * 16; ch += 1024) {
      const int node = ch >> 4, cc = (ch & 15) * 8;
      *(f16x8*)(xr_s + node * 128 + cc) =
          *(const f16x8*)(xrb + (size_t)(g * 200 + r0 + node) * 512 + chunk * 128 + cc);
    }
    for (int i = t; i < 64; i += 1024) {
      f16x2 a;
      a[0] = (_Float16)attw[chunk * 128 + 2 * i];
      a[1] = (_Float16)attw[chunk * 128 + 2 * i + 1];
      att_s[i] = __builtin_bit_cast(unsigned, a);
    }
    __syncthreads();
    for (int jj = wave; jj < 50; jj += 16) {
      const int gn = g * 200 + r0 + jj;
      const int cnt = cnts[gn];
      const unsigned char* lst = lists + (size_t)gn * NN;
#pragma unroll
      for (int r = 0; r < 4; ++r) {
        const int e = (r << 6) + lane;
        if (e < cnt) {
          const int s = lst[e];
          const int sw = s & 15;
          const _Float16* xrow = (const _Float16*)(smem) + s * 128;
          float accv[4] = {0.f, 0.f, 0.f, 0.f};
#pragma unroll 4
          for (int gi0 = 0; gi0 < 16; ++gi0) {
            F16X8U xa, raa;
            xa.v = *(const f16x8*)(xrow + (gi0 ^ sw) * 8);
            raa.v = *(const f16x8*)(xr_s + jj * 128 + gi0 * 8);
            U4F av; av.u = att4[gi0];
#pragma unroll
            for (int pq = 0; pq < 4; ++pq) {
              f16x2 z = xa.p[pq] + raa.p[pq];
              f16x2 zs = z * (_Float16)0.2f;
              f16x2 m = __builtin_elementwise_max(z, zs);
              accv[pq] = FDOT2(__builtin_bit_cast(f16x2, av.w[pq]), m, accv[pq]);
            }
          }
          const float acc = (accv[0] + accv[1]) + (accv[2] + accv[3]);
          if (chunk == 0) plog[jj * 200 + e] = acc;
          else plog[jj * 200 + e] += acc;
        }
      }
    }
  }
  __syncthreads();
  for (int jj = wave; jj < 50; jj += 16) {
    const int gn = g * 200 + r0 + jj;
    const int cnt = cnts[gn];
    const unsigned char* lst = lists + (size_t)gn * NN;
    float lg[4] = {-INFINITY, -INFINITY, -INFINITY, -INFINITY};
#pragma unroll
    for (int r = 0; r < 4; ++r) {
      const int e = (r << 6) + lane;
      if (e < cnt) lg[r] = plog[jj * 200 + e];
    }
    float mloc = fmaxf(fmaxf(lg[0], lg[1]), fmaxf(lg[2], lg[3]));
#pragma unroll
    for (int off = 32; off > 0; off >>= 1) mloc = fmaxf(mloc, __shfl_xor(mloc, off));
    float ex[4]; float ps = 0.f;
#pragma unroll
    for (int r = 0; r < 4; ++r) { ex[r] = __expf(lg[r] - mloc); ps += ex[r]; }
#pragma unroll
    for (int off = 32; off > 0; off >>= 1) ps += __shfl_xor(ps, off);
    const float denom = ps + 1e-16f;
#pragma unroll
    for (int r = 0; r < 4; ++r) {
      const int e = (r << 6) + lane;
      if (e < cnt) {
        const unsigned short ab =
            __builtin_bit_cast(unsigned short, (_Float16)(ex[r] / denom));
        plogp[jj * 200 + e] = ((unsigned)ab << 16) | (unsigned)lst[e];
      }
    }
  }
  for (int chunk = 0; chunk < 4; ++chunk) {
    __syncthreads();
    for (int ch = t; ch < 200 * 16; ch += 1024) {
      const int node = ch >> 4, gr = ch & 15;
      *(f16x8*)((_Float16*)smem + node * 128 + (gr ^ (node & 15)) * 8) =
          *(const f16x8*)(xlb + (size_t)(g * 200 + node) * 512 + chunk * 128 + gr * 8);
    }
    __syncthreads();
    float p[8] = {};
    for (int jj = wave; jj < 50; jj += 16) {
      const int gn = g * 200 + r0 + jj;
      const int cnt = cnts[gn];
      float o[8] = {};
#pragma unroll 4
      for (int e0 = 0; e0 < cnt; e0 += 4) {
        const int e = e0 + grp;
        if (e < cnt) {
          const unsigned v = plogp[jj * 200 + e];
          const int s = v & 0xFF;
          const float a =
              (float)__builtin_bit_cast(_Float16, (unsigned short)(v >> 16));
          f16x8 xv = *(const f16x8*)((const _Float16*)smem + s * 128 +
                                     (li ^ (s & 15)) * 8);
#pragma unroll
          for (int q = 0; q < 8; ++q) o[q] += a * (float)xv[q];
        }
      }
#pragma unroll
      for (int q = 0; q < 8; ++q) {
        o[q] += __shfl_xor(o[q], 16);
        o[q] += __shfl_xor(o[q], 32);
      }
      if (grp == 0) {
        const int colb = chunk * 128 + li * 8;
#pragma unroll
        for (int q = 0; q < 8; ++q) p[q] += gelu_f(o[q] + biasw[colb + q]);
      }
    }
    if (grp == 0) {
      const int slot = range * 16 + wave;
      float* pd = psum + ((size_t)slot * 64 + g) * 512 + chunk * 128 + li * 8;
      float4 a0 = {p[0], p[1], p[2], p[3]};
      float4 a1 = {p[4], p[5], p[6], p[7]};
      *(float4*)pd = a0;
      *(float4*)(pd + 4) = a1;
    }
  }
}

// ---------------------------------------------------------------------------
// K10: d_out[b][c] = (1/200) * sum over 64 partial slots
// ---------------------------------------------------------------------------
__global__ void finalize(const float* __restrict__ psum, float* __restrict__ out) {
  const int idx = blockIdx.x * 256 + threadIdx.x;  // 32768 exact
  float s = 0.f;
#pragma unroll
  for (int k = 0; k < 64; ++k) s += psum[(size_t)k * 32768 + idx];
  out[idx] = s * 0.005f;
}

// ---------------------------------------------------------------------------
extern "C" void kernel_launch(void* const* d_in, const int* in_sizes, int n_in,
                              void* d_out, int out_size, void* d_ws, size_t ws_size,
                              hipStream_t stream) {
  const float* raw_fc = (const float*)d_in[0];
  const float* gbW = (const float*)d_in[1];
  const float* gbb = (const float*)d_in[2];
  const float* feW1 = (const float*)d_in[3];
  const float* feb1 = (const float*)d_in[4];
  const float* feW2 = (const float*)d_in[5];
  const float* feb2 = (const float*)d_in[6];
  const float* ln_g = (const float*)d_in[7];
  const float* ln_b = (const float*)d_in[8];
  const float* W1l = (const float*)d_in[9];  const float* b1l = (const float*)d_in[10];
  const float* W1r = (const float*)d_in[11]; const float* b1r = (const float*)d_in[12];
  const float* att1 = (const float*)d_in[13]; const float* bias1 = (const float*)d_in[14];
  const float* W2l = (const float*)d_in[15]; const float* b2l = (const float*)d_in[16];
  const float* W2r = (const float*)d_in[17]; const float* b2r = (const float*)d_in[18];
  const float* att2 = (const float*)d_in[19]; const float* bias2 = (const float*)d_in[20];
  const float* W3l = (const float*)d_in[21]; const float* b3l = (const float*)d_in[22];
  const float* W3r = (const float*)d_in[23]; const float* b3r = (const float*)d_in[24];
  const float* att3 = (const float*)d_in[25]; const float* bias3 = (const float*)d_in[26];

  if (ws_size < 121000000) return;  // need ~115.4 MiB scratch

  char* w = (char*)d_ws;
  float* adj   = (float*)(w + 0);
  float* adjS  = (float*)(w + 10240000);
  float* meanv = (float*)(w + 20480000);
  float* stdv  = (float*)(w + 20531200);
  int* cnt1    = (int*)(w + 21401856);
  int* cnt2    = (int*)(w + 21453056);
  unsigned char* list1 = (unsigned char*)(w + 21504256);
  unsigned char* list2 = (unsigned char*)(w + 24064256);
  _Float16* bufA = (_Float16*)(w + 26624256);   // xl1 / xl2 / xl3
  _Float16* bufB = (_Float16*)(w + 52838656);   // xr1 / xr2 / xr3
  _Float16* bufC = (_Float16*)(w + 79053056);   // x2 / x3
  float* psum = (float*)(w + 105267456);        // 8,388,608 B (64 slots)
  short* Ahi  = (short*)(w + 113656064);
  short* Alo  = (short*)(w + 114168064);
  _Float16* Wt2l = (_Float16*)(w + 114680064);
  _Float16* Wt2r = (_Float16*)(w + 116777216);
  _Float16* Wt3l = (_Float16*)(w + 118874368);
  _Float16* Wt3r = (_Float16*)(w + 119922944);

  const int SMEM_L1 = 68352;    // 51200+4096+12800+256
  const int SMEM_L2 = 123904;   // 102400+8192+12800+512
  const int SMEM_L3 = 104256;   // 51200+12800+40000+256
  hipFuncSetAttribute((const void*)gat_layer<128, 1024>,
                      hipFuncAttributeMaxDynamicSharedMemorySize, SMEM_L1);
  hipFuncSetAttribute((const void*)gat_layer<256, 1024>,
                      hipFuncAttributeMaxDynamicSharedMemorySize, SMEM_L2);
  hipFuncSetAttribute((const void*)gat_l3,
                      hipFuncAttributeMaxDynamicSharedMemorySize, SMEM_L3);

  prep_A<<<1000, 256, 0, stream>>>(raw_fc, Ahi, Alo);
  transp_all<<<dim3(32, 32, 4), 256, 0, stream>>>(W2l, W2r, W3l, W3r, Wt2l, Wt2r, Wt3l, Wt3r);
  build_adj<<<625, 256, 0, stream>>>(Ahi, Alo, gbW, gbb, adj);
  symmetrize<<<dim3(64, 16), 256, 0, stream>>>(adj, adjS);
  rowstats<<<3200, 256, 0, stream>>>(adjS, meanv, stdv);
  radix_lists<<<64, 1024, 0, stream>>>(adjS, cnt1, cnt2, list1, list2);
  lin16_fused<<<800, 256, 0, stream>>>(meanv, stdv, feW1, feb1, feW2, feb2, ln_g, ln_b,
                                       W1l, b1l, W1r, b1r, bufA, bufB);
  gat_layer<128, 1024><<<dim3(64, 8), 1024, SMEM_L1, stream>>>(
      bufA, bufB, att1, bias1, cnt1, list1, bufC);
  gemm_nt<<<dim3(16, 100), 256, 0, stream>>>(bufC, Wt2l, Wt2r, b2l, b2r, bufA, bufB, 1024, 8);
  gat_layer<256, 1024><<<dim3(64, 4), 1024, SMEM_L2, stream>>>(
      bufA, bufB, att2, bias2, cnt2, list2, bufC);
  gemm_nt<<<dim3(8, 100), 256, 0, stream>>>(bufC, Wt3l, Wt3r, b3l, b3r, bufA, bufB, 512, 4);
  gat_l3<<<dim3(64, 4), 1024, SMEM_L3, stream>>>(bufA, bufB, att3, bias3, cnt2, list2, psum);
  finalize<<<128, 256, 0, stream>>>(psum, (float*)d_out);
}

// Round 12
// 903.503 us; speedup vs baseline: 1.0248x; 1.0248x over previous
//
#include <hip/hip_runtime.h>
#include <hip/hip_fp16.h>
#include <math.h>
#include <cstdint>
#include <cstddef>

#define NGRAPH 64
#define NN 200
#define ADJN 40000
#define DIN 4000
#define NNODE 12800

typedef float    f32x4 __attribute__((ext_vector_type(4)));
typedef _Float16 f16x8 __attribute__((ext_vector_type(8)));
typedef _Float16 f16x4 __attribute__((ext_vector_type(4)));
typedef _Float16 f16x2 __attribute__((ext_vector_type(2)));
typedef short    bf8v  __attribute__((ext_vector_type(8)));
typedef short    bf4v  __attribute__((ext_vector_type(4)));

union BF8U  { bf8v v; bf4v h[2]; };
union F16X8U{ f16x8 v; f16x4 h[2]; f16x2 p[4]; };
union U4F   { uint4 u; unsigned w[4]; };

__device__ __forceinline__ unsigned short f2bf(float f) {
  unsigned u = __float_as_uint(f);
  return (unsigned short)((u + 0x7fffu + ((u >> 16) & 1u)) >> 16);
}
__device__ __forceinline__ float bf2f(unsigned short s) {
  return __uint_as_float(((unsigned)s) << 16);
}
__device__ __forceinline__ float gelu_f(float x) {
  return x * 0.5f * (1.0f + erff(x * 0.70710678118654752f));
}

#if defined(__has_builtin)
#if __has_builtin(__builtin_amdgcn_fdot2)
#define FDOT2(a, b, c) __builtin_amdgcn_fdot2((a), (b), (c), false)
#endif
#endif
#ifndef FDOT2
#define FDOT2(a, b, c) ((c) + (float)(a)[0] * (float)(b)[0] + (float)(a)[1] * (float)(b)[1])
#endif

// async global->LDS, 16B per lane; lptr must be wave-uniform (HW adds lane*16)
__device__ __forceinline__ void glds16(const _Float16* g, _Float16* l) {
  __builtin_amdgcn_global_load_lds(
      (const __attribute__((address_space(1))) void*)g,
      (__attribute__((address_space(3))) void*)l, 16, 0, 0);
}

// ---------------------------------------------------------------------------
// K0: raw_fc -> hi/lo bf16 split
// ---------------------------------------------------------------------------
__global__ __launch_bounds__(256) void prep_A(const float* __restrict__ A,
                                              short* __restrict__ Ahi,
                                              short* __restrict__ Alo) {
  const int i = blockIdx.x * 256 + threadIdx.x;  // 256000 exact
  const float v = A[i];
  const unsigned short h = f2bf(v);
  Ahi[i] = (short)h;
  Alo[i] = (short)f2bf(v - bf2f(h));
}

// ---------------------------------------------------------------------------
// K0b: all 4 GEMM weights: W[k][n] f32 -> Wt[n][k] f16 (fused, blockIdx.z)
// ---------------------------------------------------------------------------
__global__ __launch_bounds__(256) void transp_all(
    const float* __restrict__ W2l, const float* __restrict__ W2r,
    const float* __restrict__ W3l, const float* __restrict__ W3r,
    _Float16* __restrict__ T2l, _Float16* __restrict__ T2r,
    _Float16* __restrict__ T3l, _Float16* __restrict__ T3r) {
  __shared__ float tile[32][33];
  const int z = blockIdx.z;
  if (z >= 2 && blockIdx.y >= 16) return;
  const float* src = (z == 0) ? W2l : (z == 1) ? W2r : (z == 2) ? W3l : W3r;
  _Float16* dst = (z == 0) ? T2l : (z == 1) ? T2r : (z == 2) ? T3l : T3r;
  const int N = (z < 2) ? 1024 : 512;
  const int K = 1024;
  const int bk = blockIdx.x * 32, bn = blockIdx.y * 32;
  const int tx = threadIdx.x & 31, ty = threadIdx.x >> 5;
#pragma unroll
  for (int r = 0; r < 32; r += 8) tile[ty + r][tx] = src[(size_t)(bk + ty + r) * N + bn + tx];
  __syncthreads();
#pragma unroll
  for (int r = 0; r < 32; r += 8)
    dst[(size_t)(bn + ty + r) * K + bk + tx] = (_Float16)tile[tx][ty + r];
}

// ---------------------------------------------------------------------------
// K1: adj = sigmoid(raw_fc @ gbW + gbb); split-bf16 MFMA.
// ---------------------------------------------------------------------------
#define BA_LOADW(WV, K0)                                                        \
  _Pragma("unroll") for (int q = 0; q < 8; ++q)                                 \
    WV[q] = W[(size_t)((K0) + kgrp * 8 + q) * ADJN + n0 + nn];

#define BA_CONV(PB, WV)                                                         \
  { bf4v h0, h1, l0, l1;                                                        \
    _Pragma("unroll") for (int i = 0; i < 4; ++i) {                             \
      unsigned short hh = (unsigned short)(__float_as_uint(WV[i]) >> 16);       \
      h0[i] = (short)hh;                                                        \
      l0[i] = (short)f2bf(WV[i] - bf2f(hh));                                    \
    }                                                                           \
    _Pragma("unroll") for (int i = 0; i < 4; ++i) {                             \
      unsigned short hh = (unsigned short)(__float_as_uint(WV[4 + i]) >> 16);   \
      h1[i] = (short)hh;                                                        \
      l1[i] = (short)f2bf(WV[4 + i] - bf2f(hh));                                \
    }                                                                           \
    *(bf4v*)(Wh[PB] + nn * 44 + kgrp * 8)     = h0;                             \
    *(bf4v*)(Wh[PB] + nn * 44 + kgrp * 8 + 4) = h1;                             \
    *(bf4v*)(Wl[PB] + nn * 44 + kgrp * 8)     = l0;                             \
    *(bf4v*)(Wl[PB] + nn * 44 + kgrp * 8 + 4) = l1;                             \
  }

#define BA_MFMA(PB, AHC, ALC)                                                   \
  _Pragma("unroll") for (int j = 0; j < 4; ++j) {                               \
    const int bc = (j * 16 + (lane & 15)) * 44 + kb;                            \
    BF8U bh, bl;                                                                \
    bh.h[0] = *(const bf4v*)(Wh[PB] + bc);                                      \
    bh.h[1] = *(const bf4v*)(Wh[PB] + bc + 4);                                  \
    bl.h[0] = *(const bf4v*)(Wl[PB] + bc);                                      \
    bl.h[1] = *(const bf4v*)(Wl[PB] + bc + 4);                                  \
    acc[j] = __builtin_amdgcn_mfma_f32_16x16x32_bf16(AHC, bh.v, acc[j], 0, 0, 0); \
    acc[j] = __builtin_amdgcn_mfma_f32_16x16x32_bf16(AHC, bl.v, acc[j], 0, 0, 0); \
    acc[j] = __builtin_amdgcn_mfma_f32_16x16x32_bf16(ALC, bh.v, acc[j], 0, 0, 0); \
  }

#define BA_LOADA(AH, AL, K0)                                                    \
  AH = *(const bf8v*)(Ahi + (size_t)arow * DIN + (K0) + kb);                    \
  AL = *(const bf8v*)(Alo + (size_t)arow * DIN + (K0) + kb);

__global__ __launch_bounds__(256) void build_adj(
    const short* __restrict__ Ahi, const short* __restrict__ Alo,
    const float* __restrict__ W, const float* __restrict__ bias,
    float* __restrict__ adj) {
  __shared__ short Wh[2][64 * 44], Wl[2][64 * 44];
  const int t = threadIdx.x, wave = t >> 6, lane = t & 63;
  const int n0 = blockIdx.x * 64;
  const int nn = t & 63, kgrp = t >> 6;   // staging coords: one n, 8 k
  const int kb = (lane >> 4) * 8;
  const int arow = wave * 16 + (lane & 15);
  f32x4 acc[4] = {};
  float wva[8], wvb[8];
  bf8v ahs0, als0, ahs1, als1;
  BA_LOADW(wva, 0)
  BA_LOADA(ahs0, als0, 0)
  BA_LOADW(wvb, 32)
  BA_LOADA(ahs1, als1, 32)
  BA_CONV(0, wva)
  for (int it = 0; it < 124; it += 2) {
    __syncthreads();
    {
      const bf8v ahc = ahs0, alc = als0;
      if (it + 2 < 125) {
        const int k2 = (it + 2) * 32;
        BA_LOADW(wva, k2)
        BA_LOADA(ahs0, als0, k2)
      }
      BA_MFMA(0, ahc, alc)
      BA_CONV(1, wvb)
    }
    __syncthreads();
    {
      const bf8v ahc = ahs1, alc = als1;
      if (it + 3 < 125) {
        const int k2 = (it + 3) * 32;
        BA_LOADW(wvb, k2)
        BA_LOADA(ahs1, als1, k2)
      }
      BA_MFMA(1, ahc, alc)
      if (it + 2 < 125) BA_CONV(0, wva)
    }
  }
  __syncthreads();
  BA_MFMA(0, ahs0, als0)
#pragma unroll
  for (int j = 0; j < 4; ++j) {
    const int col = n0 + j * 16 + (lane & 15);
    const float bb = bias[col];
#pragma unroll
    for (int vv = 0; vv < 4; ++vv) {
      const int row = wave * 16 + (lane >> 4) * 4 + vv;
      float x = acc[j][vv] + bb;
      adj[(size_t)row * ADJN + col] = 1.0f / (1.0f + __expf(-x));
    }
  }
}

// ---------------------------------------------------------------------------
// K2: adjS = 0.5*(adj + adj^T), LDS-tiled
// ---------------------------------------------------------------------------
__global__ __launch_bounds__(256) void symmetrize(const float* __restrict__ adj,
                                                  float* __restrict__ adjS) {
  __shared__ float tl[64][65];
  const int g = blockIdx.x;
  const int i0 = (blockIdx.y >> 2) * 64, j0 = (blockIdx.y & 3) * 64;
  const int tx = threadIdx.x & 63, ty = threadIdx.x >> 6;
  const float* ag = adj + (size_t)g * ADJN;
#pragma unroll
  for (int r = 0; r < 64; r += 4) {
    const int jr = j0 + ty + r;
    tl[ty + r][tx] = (jr < NN && i0 + tx < NN) ? ag[jr * NN + i0 + tx] : 0.f;
  }
  __syncthreads();
#pragma unroll
  for (int r = 0; r < 64; r += 4) {
    const int i = i0 + ty + r, j = j0 + tx;
    if (i < NN && j < NN)
      adjS[(size_t)g * ADJN + i * NN + j] = 0.5f * (ag[i * NN + j] + tl[tx][ty + r]);
  }
}

// ---------------------------------------------------------------------------
// K2b: per-row mean / std(ddof=1)
// ---------------------------------------------------------------------------
__global__ __launch_bounds__(256) void rowstats(const float* __restrict__ adjS,
                                                float* __restrict__ meanv,
                                                float* __restrict__ stdv) {
  const int row = blockIdx.x * 4 + (threadIdx.x >> 6);
  const int lane = threadIdx.x & 63;
  const float* r = adjS + (size_t)row * NN;
  float s = 0.f, q = 0.f;
#pragma unroll
  for (int k = 0; k < 4; ++k) {
    int i = k * 64 + lane;
    if (i < NN) { float v = r[i]; s += v; q += v * v; }
  }
#pragma unroll
  for (int off = 32; off > 0; off >>= 1) { s += __shfl_xor(s, off); q += __shfl_xor(q, off); }
  if (lane == 0) {
    float m = s * (1.0f / 200.0f);
    float var = (q - 200.0f * m * m) * (1.0f / 199.0f);
    var = fmaxf(var, 0.f);
    meanv[row] = m;
    stdv[row] = sqrtf(var) + 1e-6f;
  }
}

// ---------------------------------------------------------------------------
// K3: fused radix-select (4-copy hist) + per-dst neighbor lists. 64 blocks.
// ---------------------------------------------------------------------------
__global__ __launch_bounds__(1024) void radix_lists(
    const float* __restrict__ adjS,
    int* __restrict__ cnt1, int* __restrict__ cnt2,
    unsigned char* __restrict__ list1, unsigned char* __restrict__ list2) {
  __shared__ unsigned hist[4 * 2048];
  __shared__ unsigned s_pref, s_cA;
  const int g = blockIdx.x, t = threadIdx.x, lane = t & 63, wave = t >> 6;
  const float* v = adjS + (size_t)g * ADJN;
  unsigned prefix = 0, pmask = 0, cA = 0;
  const int shifts[3] = {20, 9, 0};
  const int widths[3] = {2048, 2048, 512};
  for (int pass = 0; pass < 3; ++pass) {
    const int nb = widths[pass], sh = shifts[pass];
    for (int i = t; i < 8192; i += 1024) hist[i] = 0u;
    __syncthreads();
    const int cpy = (lane & 3) * 2048;
    for (int e = t; e < ADJN; e += 1024) {
      unsigned u = __float_as_uint(v[e]);
      if ((u & pmask) == prefix) atomicAdd(&hist[cpy + ((u >> sh) & (nb - 1))], 1u);
    }
    __syncthreads();
    if (t < 64) {
      const int CH = nb >> 6;
      unsigned lsum = 0;
      for (int i = 0; i < CH; ++i) {
        const int b = t * CH + i;
        lsum += hist[b] + hist[2048 + b] + hist[4096 + b] + hist[6144 + b];
      }
      unsigned s = lsum;
#pragma unroll
      for (int off = 1; off < 64; off <<= 1) {
        unsigned o = __shfl_down(s, off);
        if (lane + off < 64) s += o;
      }
      const unsigned need = 10000u - cA;
      unsigned sn = __shfl_down(s, 1);
      const unsigned snext = (lane == 63) ? 0u : sn;
      if (s >= need && snext < need) {
        unsigned cum = snext;
        int bsel = t * CH;
        for (int i = CH - 1; i >= 0; --i) {
          const int b = t * CH + i;
          unsigned hb = hist[b] + hist[2048 + b] + hist[4096 + b] + hist[6144 + b];
          if (cum + hb >= need) { bsel = b; break; }
          cum += hb;
        }
        s_pref = prefix | ((unsigned)bsel << sh);
        s_cA = cA + cum;
      }
    }
    __syncthreads();
    prefix = s_pref; cA = s_cA;
    pmask |= (unsigned)(widths[pass] - 1) << sh;
    __syncthreads();
  }
  const float tv = __uint_as_float(prefix);
  for (int j = wave; j < NN; j += 16) {
    const float* row = adjS + (size_t)g * ADJN + (size_t)j * NN;
    unsigned char* l1 = list1 + ((size_t)g * NN + j) * NN;
    unsigned char* l2 = list2 + ((size_t)g * NN + j) * NN;
    int c1 = 0, c2 = 0;
#pragma unroll
    for (int r = 0; r < 4; ++r) {
      int i = r * 64 + lane;
      bool p1 = false, p2 = false;
      if (i < NN) { float vv = row[i]; p1 = (vv >= tv); p2 = p1 && (i != j); }
      unsigned long long b1 = __ballot(p1);
      unsigned long long b2 = __ballot(p2);
      unsigned long long below = (lane == 0) ? 0ull : ((~0ull) >> (64 - lane));
      if (p1) l1[c1 + __popcll(b1 & below)] = (unsigned char)i;
      if (p2) l2[c2 + __popcll(b2 & below)] = (unsigned char)i;
      c1 += (int)__popcll(b1); c2 += (int)__popcll(b2);
    }
    if (lane == 0) {
      l2[c2] = (unsigned char)j;
      cnt1[g * NN + j] = c1;
      cnt2[g * NN + j] = c2 + 1;
    }
  }
}

// ---------------------------------------------------------------------------
// K6: fused node-MLP(2->8 gelu ->16)+LN(16) -> xl1/xr1 via MFMA (K=16 padded)
// ---------------------------------------------------------------------------
__global__ __launch_bounds__(256) void lin16_fused(
    const float* __restrict__ meanv, const float* __restrict__ stdv,
    const float* __restrict__ feW1, const float* __restrict__ feb1,
    const float* __restrict__ feW2, const float* __restrict__ feb2,
    const float* __restrict__ ln_g, const float* __restrict__ ln_b,
    const float* __restrict__ Wl, const float* __restrict__ bl,
    const float* __restrict__ Wr, const float* __restrict__ br,
    _Float16* __restrict__ outl, _Float16* __restrict__ outr) {
  __shared__ _Float16 Wt[1024 * 20];
  __shared__ float x0s[16][17];
  const int t = threadIdx.x, wave = t >> 6, lane = t & 63;
  const int mbase = blockIdx.x * 16;
  {
    const int n = t >> 4, o = t & 15;
    const float mu = meanv[mbase + n], sd = stdv[mbase + n];
    float h1[8];
#pragma unroll
    for (int k = 0; k < 8; ++k) h1[k] = gelu_f(mu * feW1[k] + sd * feW1[8 + k] + feb1[k]);
    float h2 = feb2[o];
#pragma unroll
    for (int k = 0; k < 8; ++k) h2 += h1[k] * feW2[k * 16 + o];
    float s = h2;
#pragma unroll
    for (int off = 1; off < 16; off <<= 1) s += __shfl_xor(s, off);
    s *= (1.0f / 16.0f);
    const float d = h2 - s;
    float vv = d * d;
#pragma unroll
    for (int off = 1; off < 16; off <<= 1) vv += __shfl_xor(vv, off);
    vv *= (1.0f / 16.0f);
    x0s[n][o] = d * (1.0f / sqrtf(vv + 1e-5f)) * ln_g[o] + ln_b[o];
  }
  __syncthreads();
  const int mrow = lane & 15, kg = lane >> 4;
  F16X8U af;
#pragma unroll
  for (int q = 0; q < 8; ++q) af.v[q] = (_Float16)0.f;
  if (kg < 2) {
#pragma unroll
    for (int q = 0; q < 8; ++q) af.v[q] = (_Float16)x0s[mrow][kg * 8 + q];
  }
#pragma unroll
  for (int mat = 0; mat < 2; ++mat) {
    if (mat) __syncthreads();
    const float* Wsrc = mat ? Wr : Wl;
    for (int i = t; i < 4096; i += 256) {
      const int k = i >> 8, n4 = (i & 255) * 4;
      float4 wv = *(const float4*)(Wsrc + (size_t)k * 1024 + n4);
      Wt[(n4 + 0) * 20 + k] = (_Float16)wv.x;
      Wt[(n4 + 1) * 20 + k] = (_Float16)wv.y;
      Wt[(n4 + 2) * 20 + k] = (_Float16)wv.z;
      Wt[(n4 + 3) * 20 + k] = (_Float16)wv.w;
    }
    __syncthreads();
    const float* bias = mat ? br : bl;
    _Float16* out = mat ? outr : outl;
#pragma unroll
    for (int nt = 0; nt < 16; ++nt) {
      const int n0 = wave * 256 + nt * 16;
      F16X8U bfv;
#pragma unroll
      for (int q = 0; q < 8; ++q) bfv.v[q] = (_Float16)0.f;
      if (kg < 2) bfv.v = *(const f16x8*)(Wt + (n0 + mrow) * 20 + kg * 8);
      f32x4 acc = {};
      acc = __builtin_amdgcn_mfma_f32_16x16x32_f16(af.v, bfv.v, acc, 0, 0, 0);
      const int col = n0 + mrow;
      const float bb = bias[col];
#pragma unroll
      for (int j = 0; j < 4; ++j)
        out[(size_t)(mbase + kg * 4 + j) * 1024 + col] = (_Float16)(acc[j] + bb);
    }
  }
}

// ---------------------------------------------------------------------------
// K9: NT-GEMM 128x128 tile, BK=64, dbuf LDS via global_load_lds (16B)
// ---------------------------------------------------------------------------
__global__ __launch_bounds__(256, 2) void gemm_nt(
    const _Float16* __restrict__ A,
    const _Float16* __restrict__ Bt0, const _Float16* __restrict__ Bt1,
    const float* __restrict__ b0, const float* __restrict__ b1,
    _Float16* __restrict__ out0, _Float16* __restrict__ out1,
    int Nhalf, int tilesPerHalf) {
  __shared__ _Float16 As[2][128 * 64];
  __shared__ _Float16 Bs[2][128 * 64];
  const int mbase = blockIdx.y * 128;
  const int hsel = blockIdx.x / tilesPerHalf;
  const int ncol0 = (blockIdx.x % tilesPerHalf) * 128;
  const _Float16* Bt = hsel ? Bt1 : Bt0;
  const float* bias = hsel ? b1 : b0;
  _Float16* out = hsel ? out1 : out0;
  const int t = threadIdx.x, wave = t >> 6, lane = t & 63;
  const int wm = wave >> 1, wn = wave & 1;
  f32x4 acc[4][4] = {};
  const int srow = lane >> 3;
  const int sg = (lane & 7) ^ srow;
#pragma unroll
  for (int c = 0; c < 4; ++c) {
    const int rbase = wave * 32 + c * 8;
    glds16(A + (size_t)(mbase + rbase + srow) * 1024 + sg * 8, As[0] + rbase * 64);
    glds16(Bt + (size_t)(ncol0 + rbase + srow) * 1024 + sg * 8, Bs[0] + rbase * 64);
  }
  __syncthreads();
  for (int kt = 0; kt < 16; ++kt) {
    const int p = kt & 1;
    if (kt < 15) {
      const int k0 = (kt + 1) * 64;
#pragma unroll
      for (int c = 0; c < 4; ++c) {
        const int rbase = wave * 32 + c * 8;
        glds16(A + (size_t)(mbase + rbase + srow) * 1024 + k0 + sg * 8, As[p ^ 1] + rbase * 64);
        glds16(Bt + (size_t)(ncol0 + rbase + srow) * 1024 + k0 + sg * 8, Bs[p ^ 1] + rbase * 64);
      }
    }
#pragma unroll
    for (int ks = 0; ks < 2; ++ks) {
      F16X8U af[4], bfv[4];
#pragma unroll
      for (int m = 0; m < 4; ++m) {
        const int row = wm * 64 + m * 16 + (lane & 15);
        const int kk = ks * 32 + (lane >> 4) * 8;
        af[m].v = *(const f16x8*)(As[p] + row * 64 + (kk ^ ((row & 7) << 3)));
      }
#pragma unroll
      for (int j = 0; j < 4; ++j) {
        const int row = wn * 64 + j * 16 + (lane & 15);
        const int kk = ks * 32 + (lane >> 4) * 8;
        bfv[j].v = *(const f16x8*)(Bs[p] + row * 64 + (kk ^ ((row & 7) << 3)));
      }
#pragma unroll
      for (int j = 0; j < 4; ++j)
#pragma unroll
        for (int m = 0; m < 4; ++m)
          acc[m][j] = __builtin_amdgcn_mfma_f32_16x16x32_f16(af[m].v, bfv[j].v, acc[m][j], 0, 0, 0);
    }
    __syncthreads();
  }
#pragma unroll
  for (int j = 0; j < 4; ++j) {
    const int col = ncol0 + wn * 64 + j * 16 + (lane & 15);
    const float bb = bias[col];
#pragma unroll
    for (int m = 0; m < 4; ++m) {
#pragma unroll
      for (int vv = 0; vv < 4; ++vv) {
        const int row = mbase + wm * 64 + m * 16 + (lane >> 4) * 4 + vv;
        out[(size_t)row * Nhalf + col] = (_Float16)(acc[m][j][vv] + bb);
      }
    }
  }
}

// ---------------------------------------------------------------------------
// K7: GATv2 layer v2 (R10 form): LINEAR xl layout + lane-rotated logit
// gathers, att via uint4, packed (alpha|s) agg; agg loop unrolled x4.
// ---------------------------------------------------------------------------
template <int C, int HC>
__global__ __launch_bounds__(1024, 4) void gat_layer(
    const _Float16* __restrict__ xlb, const _Float16* __restrict__ xrb,
    const float* __restrict__ attw, const float* __restrict__ biasw,
    const int* __restrict__ cnts, const unsigned char* __restrict__ lists,
    _Float16* __restrict__ outb) {
  extern __shared__ char smem[];
  constexpr int XLB = 200 * C * 2;
  constexpr int XRW = 16 * C * 2;
  _Float16* xr_s = (_Float16*)(smem + XLB);
  unsigned* awp = (unsigned*)(smem + XLB + XRW);              // 16*200*4
  unsigned* att_s = (unsigned*)(smem + XLB + XRW + 12800);
  const int g = blockIdx.x;
  const int hd = blockIdx.y;
  const int t = threadIdx.x, wave = t >> 6, lane = t & 63;
  constexpr int NGR = C / 8;          // 16B granules per row
  constexpr int GRP = (C == 128) ? 16 : 32;
  constexpr int NG = 64 / GRP;
  const int grp = lane / GRP, li = lane % GRP;
  const int rc = lane & (NGR - 1) & 31;

  for (int ch = t; ch < 200 * NGR; ch += 1024) {
    const int node = ch / NGR, cc = (ch % NGR) * 8;
    *(f16x8*)(smem + (node * C + cc) * 2) =
        *(const f16x8*)(xlb + (size_t)(g * 200 + node) * HC + hd * C + cc);
  }
  for (int i = t; i < C / 2; i += 1024) {
    f16x2 a;
    a[0] = (_Float16)attw[hd * C + 2 * i];
    a[1] = (_Float16)attw[hd * C + 2 * i + 1];
    att_s[i] = __builtin_bit_cast(unsigned, a);
  }
  __syncthreads();

  _Float16* xr_w = xr_s + wave * C;
  const uint4* att4 = (const uint4*)att_s;
  f16x8 xrreg;
  if (lane < NGR)
    xrreg = *(const f16x8*)(xrb + (size_t)(g * 200 + wave) * HC + hd * C + lane * 8);

  for (int jj = wave; jj < 200; jj += 16) {
    const int gn = g * 200 + jj;
    const int cnt = cnts[gn];
    const unsigned char* lst = lists + (size_t)gn * NN;
    if (lane < NGR) {
      *(f16x8*)(xr_w + lane * 8) = xrreg;
      if (jj + 16 < 200)
        xrreg = *(const f16x8*)(xrb + (size_t)(gn + 16) * HC + hd * C + lane * 8);
    }
    float lg[4] = {-INFINITY, -INFINITY, -INFINITY, -INFINITY};
    int sreg[4];
#pragma unroll
    for (int r = 0; r < 4; ++r) {
      const int e = (r << 6) + lane;
      if (e < cnt) {
        const int s = lst[e];
        sreg[r] = s;
        const _Float16* xrow = (const _Float16*)(smem) + s * C;
        float accv[4] = {0.f, 0.f, 0.f, 0.f};
#pragma unroll 4
        for (int gi0 = 0; gi0 < NGR; ++gi0) {
          const int gi = (gi0 + rc) & (NGR - 1);
          const int cc = gi * 8;
          F16X8U xa, raa;
          xa.v = *(const f16x8*)(xrow + cc);
          raa.v = *(const f16x8*)(xr_w + cc);
          U4F av; av.u = att4[gi];
#pragma unroll
          for (int pq = 0; pq < 4; ++pq) {
            f16x2 z = xa.p[pq] + raa.p[pq];
            f16x2 zs = z * (_Float16)0.2f;
            f16x2 m = __builtin_elementwise_max(z, zs);
            accv[pq] = FDOT2(__builtin_bit_cast(f16x2, av.w[pq]), m, accv[pq]);
          }
        }
        lg[r] = (accv[0] + accv[1]) + (accv[2] + accv[3]);
      }
    }
    float mloc = fmaxf(fmaxf(lg[0], lg[1]), fmaxf(lg[2], lg[3]));
#pragma unroll
    for (int off = 32; off > 0; off >>= 1) mloc = fmaxf(mloc, __shfl_xor(mloc, off));
    float ex[4]; float ps = 0.f;
#pragma unroll
    for (int r = 0; r < 4; ++r) { ex[r] = __expf(lg[r] - mloc); ps += ex[r]; }
#pragma unroll
    for (int off = 32; off > 0; off >>= 1) ps += __shfl_xor(ps, off);
    const float denom = ps + 1e-16f;
#pragma unroll
    for (int r = 0; r < 4; ++r) {
      const int e = (r << 6) + lane;
      if (e < cnt) {
        const unsigned short ab =
            __builtin_bit_cast(unsigned short, (_Float16)(ex[r] / denom));
        awp[wave * 200 + e] = ((unsigned)ab << 16) | (unsigned)sreg[r];
      }
    }
    float o[8] = {};
#pragma unroll 4
    for (int e0 = 0; e0 < cnt; e0 += NG) {
      const int e = e0 + grp;
      if (e < cnt) {
        const unsigned v = awp[wave * 200 + e];
        const int s = v & 0xFF;
        const float a =
            (float)__builtin_bit_cast(_Float16, (unsigned short)(v >> 16));
        f16x8 xv = *(const f16x8*)((const _Float16*)smem + s * C + li * 8);
#pragma unroll
        for (int q = 0; q < 8; ++q) o[q] += a * (float)xv[q];
      }
    }
#pragma unroll
    for (int q = 0; q < 8; ++q) {
      if constexpr (GRP == 16) o[q] += __shfl_xor(o[q], 16);
      o[q] += __shfl_xor(o[q], 32);
    }
    if (grp == 0) {
      const int colb = hd * C + li * 8;
      f16x8 ov;
#pragma unroll
      for (int q = 0; q < 8; ++q) ov[q] = (_Float16)gelu_f(o[q] + biasw[colb + q]);
      *(f16x8*)(outb + (size_t)gn * HC + colb) = ov;
    }
  }
}

// ---------------------------------------------------------------------------
// K7-L3: GATv2 (H=1,C=512) chunked v2 (R10 form): linear layout + rotation +
// packed agg; agg loop unrolled x4.
// ---------------------------------------------------------------------------
__global__ __launch_bounds__(1024, 4) void gat_l3(
    const _Float16* __restrict__ xlb, const _Float16* __restrict__ xrb,
    const float* __restrict__ attw, const float* __restrict__ biasw,
    const int* __restrict__ cnts, const unsigned char* __restrict__ lists,
    float* __restrict__ psum) {
  extern __shared__ char smem[];
  _Float16* xr_s = (_Float16*)(smem + 51200);
  float* plog = (float*)(smem + 64000);
  unsigned* plogp = (unsigned*)(smem + 64000);
  unsigned* att_s = (unsigned*)(smem + 104000);
  const int g = blockIdx.x, range = blockIdx.y, r0 = range * 50;
  const int t = threadIdx.x, wave = t >> 6, lane = t & 63;
  const int grp = lane >> 4, li = lane & 15;
  const int rc = lane & 15;
  const uint4* att4 = (const uint4*)att_s;

  for (int chunk = 0; chunk < 4; ++chunk) {
    if (chunk) __syncthreads();
    for (int ch = t; ch < 200 * 16; ch += 1024) {
      const int node = ch >> 4, cc = (ch & 15) * 8;
      *(f16x8*)(smem + (node * 128 + cc) * 2) =
          *(const f16x8*)(xlb + (size_t)(g * 200 + node) * 512 + chunk * 128 + cc);
    }
    for (int ch = t; ch < 50 * 16; ch += 1024) {
      const int node = ch >> 4, cc = (ch & 15) * 8;
      *(f16x8*)(xr_s + node * 128 + cc) =
          *(const f16x8*)(xrb + (size_t)(g * 200 + r0 + node) * 512 + chunk * 128 + cc);
    }
    for (int i = t; i < 64; i += 1024) {
      f16x2 a;
      a[0] = (_Float16)attw[chunk * 128 + 2 * i];
      a[1] = (_Float16)attw[chunk * 128 + 2 * i + 1];
      att_s[i] = __builtin_bit_cast(unsigned, a);
    }
    __syncthreads();
    for (int jj = wave; jj < 50; jj += 16) {
      const int gn = g * 200 + r0 + jj;
      const int cnt = cnts[gn];
      const unsigned char* lst = lists + (size_t)gn * NN;
#pragma unroll
      for (int r = 0; r < 4; ++r) {
        const int e = (r << 6) + lane;
        if (e < cnt) {
          const int s = lst[e];
          const _Float16* xrow = (const _Float16*)(smem) + s * 128;
          float accv[4] = {0.f, 0.f, 0.f, 0.f};
#pragma unroll 4
          for (int gi0 = 0; gi0 < 16; ++gi0) {
            const int gi = (gi0 + rc) & 15;
            const int cc = gi * 8;
            F16X8U xa, raa;
            xa.v = *(const f16x8*)(xrow + cc);
            raa.v = *(const f16x8*)(xr_s + jj * 128 + cc);
            U4F av; av.u = att4[gi];
#pragma unroll
            for (int pq = 0; pq < 4; ++pq) {
              f16x2 z = xa.p[pq] + raa.p[pq];
              f16x2 zs = z * (_Float16)0.2f;
              f16x2 m = __builtin_elementwise_max(z, zs);
              accv[pq] = FDOT2(__builtin_bit_cast(f16x2, av.w[pq]), m, accv[pq]);
            }
          }
          const float acc = (accv[0] + accv[1]) + (accv[2] + accv[3]);
          if (chunk == 0) plog[jj * 200 + e] = acc;
          else plog[jj * 200 + e] += acc;
        }
      }
    }
  }
  __syncthreads();
  for (int jj = wave; jj < 50; jj += 16) {
    const int gn = g * 200 + r0 + jj;
    const int cnt = cnts[gn];
    const unsigned char* lst = lists + (size_t)gn * NN;
    float lg[4] = {-INFINITY, -INFINITY, -INFINITY, -INFINITY};
#pragma unroll
    for (int r = 0; r < 4; ++r) {
      const int e = (r << 6) + lane;
      if (e < cnt) lg[r] = plog[jj * 200 + e];
    }
    float mloc = fmaxf(fmaxf(lg[0], lg[1]), fmaxf(lg[2], lg[3]));
#pragma unroll
    for (int off = 32; off > 0; off >>= 1) mloc = fmaxf(mloc, __shfl_xor(mloc, off));
    float ex[4]; float ps = 0.f;
#pragma unroll
    for (int r = 0; r < 4; ++r) { ex[r] = __expf(lg[r] - mloc); ps += ex[r]; }
#pragma unroll
    for (int off = 32; off > 0; off >>= 1) ps += __shfl_xor(ps, off);
    const float denom = ps + 1e-16f;
#pragma unroll
    for (int r = 0; r < 4; ++r) {
      const int e = (r << 6) + lane;
      if (e < cnt) {
        const unsigned short ab =
            __builtin_bit_cast(unsigned short, (_Float16)(ex[r] / denom));
        plogp[jj * 200 + e] = ((unsigned)ab << 16) | (unsigned)lst[e];
      }
    }
  }
  for (int chunk = 0; chunk < 4; ++chunk) {
    __syncthreads();
    for (int ch = t; ch < 200 * 16; ch += 1024) {
      const int node = ch >> 4, cc = (ch & 15) * 8;
      *(f16x8*)(smem + (node * 128 + cc) * 2) =
          *(const f16x8*)(xlb + (size_t)(g * 200 + node) * 512 + chunk * 128 + cc);
    }
    __syncthreads();
    float p[8] = {};
    for (int jj = wave; jj < 50; jj += 16) {
      const int gn = g * 200 + r0 + jj;
      const int cnt = cnts[gn];
      float o[8] = {};
#pragma unroll 4
      for (int e0 = 0; e0 < cnt; e0 += 4) {
        const int e = e0 + grp;
        if (e < cnt) {
          const unsigned v = plogp[jj * 200 + e];
          const int s = v & 0xFF;
          const float a =
              (float)__builtin_bit_cast(_Float16, (unsigned short)(v >> 16));
          f16x8 xv = *(const f16x8*)((const _Float16*)smem + s * 128 + li * 8);
#pragma unroll
          for (int q = 0; q < 8; ++q) o[q] += a * (float)xv[q];
        }
      }
#pragma unroll
      for (int q = 0; q < 8; ++q) {
        o[q] += __shfl_xor(o[q], 16);
        o[q] += __shfl_xor(o[q], 32);
      }
      if (grp == 0) {
        const int colb = chunk * 128 + li * 8;
#pragma unroll
        for (int q = 0; q < 8; ++q) p[q] += gelu_f(o[q] + biasw[colb + q]);
      }
    }
    if (grp == 0) {
      const int slot = range * 16 + wave;
      float* pd = psum + ((size_t)slot * 64 + g) * 512 + chunk * 128 + li * 8;
      float4 a0 = {p[0], p[1], p[2], p[3]};
      float4 a1 = {p[4], p[5], p[6], p[7]};
      *(float4*)pd = a0;
      *(float4*)(pd + 4) = a1;
    }
  }
}

// ---------------------------------------------------------------------------
// K10: d_out[b][c] = (1/200) * sum over 64 partial slots
// ---------------------------------------------------------------------------
__global__ void finalize(const float* __restrict__ psum, float* __restrict__ out) {
  const int idx = blockIdx.x * 256 + threadIdx.x;  // 32768 exact
  float s = 0.f;
#pragma unroll
  for (int k = 0; k < 64; ++k) s += psum[(size_t)k * 32768 + idx];
  out[idx] = s * 0.005f;
}

// ---------------------------------------------------------------------------
extern "C" void kernel_launch(void* const* d_in, const int* in_sizes, int n_in,
                              void* d_out, int out_size, void* d_ws, size_t ws_size,
                              hipStream_t stream) {
  const float* raw_fc = (const float*)d_in[0];
  const float* gbW = (const float*)d_in[1];
  const float* gbb = (const float*)d_in[2];
  const float* feW1 = (const float*)d_in[3];
  const float* feb1 = (const float*)d_in[4];
  const float* feW2 = (const float*)d_in[5];
  const float* feb2 = (const float*)d_in[6];
  const float* ln_g = (const float*)d_in[7];
  const float* ln_b = (const float*)d_in[8];
  const float* W1l = (const float*)d_in[9];  const float* b1l = (const float*)d_in[10];
  const float* W1r = (const float*)d_in[11]; const float* b1r = (const float*)d_in[12];
  const float* att1 = (const float*)d_in[13]; const float* bias1 = (const float*)d_in[14];
  const float* W2l = (const float*)d_in[15]; const float* b2l = (const float*)d_in[16];
  const float* W2r = (const float*)d_in[17]; const float* b2r = (const float*)d_in[18];
  const float* att2 = (const float*)d_in[19]; const float* bias2 = (const float*)d_in[20];
  const float* W3l = (const float*)d_in[21]; const float* b3l = (const float*)d_in[22];
  const float* W3r = (const float*)d_in[23]; const float* b3r = (const float*)d_in[24];
  const float* att3 = (const float*)d_in[25]; const float* bias3 = (const float*)d_in[26];

  if (ws_size < 121000000) return;  // need ~115.4 MiB scratch

  char* w = (char*)d_ws;
  float* adj   = (float*)(w + 0);
  float* adjS  = (float*)(w + 10240000);
  float* meanv = (float*)(w + 20480000);
  float* stdv  = (float*)(w + 20531200);
  int* cnt1    = (int*)(w + 21401856);
  int* cnt2    = (int*)(w + 21453056);
  unsigned char* list1 = (unsigned char*)(w + 21504256);
  unsigned char* list2 = (unsigned char*)(w + 24064256);
  _Float16* bufA = (_Float16*)(w + 26624256);   // xl1 / xl2 / xl3
  _Float16* bufB = (_Float16*)(w + 52838656);   // xr1 / xr2 / xr3
  _Float16* bufC = (_Float16*)(w + 79053056);   // x2 / x3
  float* psum = (float*)(w + 105267456);        // 8,388,608 B (64 slots)
  short* Ahi  = (short*)(w + 113656064);
  short* Alo  = (short*)(w + 114168064);
  _Float16* Wt2l = (_Float16*)(w + 114680064);
  _Float16* Wt2r = (_Float16*)(w + 116777216);
  _Float16* Wt3l = (_Float16*)(w + 118874368);
  _Float16* Wt3r = (_Float16*)(w + 119922944);

  const int SMEM_L1 = 68352;    // 51200+4096+12800+256
  const int SMEM_L2 = 123904;   // 102400+8192+12800+512
  const int SMEM_L3 = 104256;   // 51200+12800+40000+256
  hipFuncSetAttribute((const void*)gat_layer<128, 1024>,
                      hipFuncAttributeMaxDynamicSharedMemorySize, SMEM_L1);
  hipFuncSetAttribute((const void*)gat_layer<256, 1024>,
                      hipFuncAttributeMaxDynamicSharedMemorySize, SMEM_L2);
  hipFuncSetAttribute((const void*)gat_l3,
                      hipFuncAttributeMaxDynamicSharedMemorySize, SMEM_L3);

  prep_A<<<1000, 256, 0, stream>>>(raw_fc, Ahi, Alo);
  transp_all<<<dim3(32, 32, 4), 256, 0, stream>>>(W2l, W2r, W3l, W3r, Wt2l, Wt2r, Wt3l, Wt3r);
  build_adj<<<625, 256, 0, stream>>>(Ahi, Alo, gbW, gbb, adj);
  symmetrize<<<dim3(64, 16), 256, 0, stream>>>(adj, adjS);
  rowstats<<<3200, 256, 0, stream>>>(adjS, meanv, stdv);
  radix_lists<<<64, 1024, 0, stream>>>(adjS, cnt1, cnt2, list1, list2);
  lin16_fused<<<800, 256, 0, stream>>>(meanv, stdv, feW1, feb1, feW2, feb2, ln_g, ln_b,
                                       W1l, b1l, W1r, b1r, bufA, bufB);
  gat_layer<128, 1024><<<dim3(64, 8), 1024, SMEM_L1, stream>>>(
      bufA, bufB, att1, bias1, cnt1, list1, bufC);
  gemm_nt<<<dim3(16, 100), 256, 0, stream>>>(bufC, Wt2l, Wt2r, b2l, b2r, bufA, bufB, 1024, 8);
  gat_layer<256, 1024><<<dim3(64, 4), 1024, SMEM_L2, stream>>>(
      bufA, bufB, att2, bias2, cnt2, list2, bufC);
  gemm_nt<<<dim3(8, 100), 256, 0, stream>>>(bufC, Wt3l, Wt3r, b3l, b3r, bufA, bufB, 512, 4);
  gat_l3<<<dim3(64, 4), 1024, SMEM_L3, stream>>>(bufA, bufB, att3, bias3, cnt2, list2, psum);
  finalize<<<128, 256, 0, stream>>>(psum, (float*)d_out);
}